// Round 6
// baseline (619.615 us; speedup 1.0000x reference)
//
#include <hip/hip_runtime.h>

// DIAGNOSTIC BISECT ROUND — deliberately naive, pure-f32, zero shared machinery.
// out = d ∘ (A @ ((d∘X) @ W^T)) + b,  d = rsqrt(clip(rowsum(A),1e-6))
// B=4, N=2048, F=128. No MFMA, no bf16, no LDS, no shuffles, no syncthreads.
// One thread per output element everywhere. If THIS fails, the problem is my
// understanding of the harness/reference, not kernel optimization machinery.
// Z staged per-batch (1 MB f32) in d_ws -> 8 small launches, ws need 1.08 MB
// (R4's passed gate proved ws_size >= 2.13 MB).

#define NN 2048
#define FF 128
#define WS_NEED (32768u + (unsigned)(NN * FF * 4))   // dinv (32KB) + Z batch (1MB)

// ---- k1: one THREAD per row: dinv[r] = rsqrt(max(sum_m A[r][m], 1e-6)) -----
__global__ void k1_deg(const float* __restrict__ A, float* __restrict__ dinv) {
    int r = blockIdx.x * blockDim.x + threadIdx.x;   // 0..8191
    if (r >= 4 * NN) return;
    const float* row = A + (size_t)r * NN;
    float s = 0.f;
    for (int m = 0; m < NN; ++m) s += row[m];
    dinv[r] = rsqrtf(fmaxf(s, 1e-6f));
}

// ---- k2: one thread per (m,o) of batch b: Z[m][o] = dinv[b,m]*sum_f X[b,m,f]W[o,f]
__global__ void k2_z(const float* __restrict__ X, const float* __restrict__ W,
                     const float* __restrict__ dinv, float* __restrict__ Z, int b) {
    int tid = blockIdx.x * blockDim.x + threadIdx.x; // 0..NN*FF-1
    if (tid >= NN * FF) return;
    int m = tid >> 7, o = tid & 127;
    const float* xr = X + ((size_t)b * NN + m) * FF;
    const float* wr = W + (size_t)o * FF;
    float s = 0.f;
    for (int f = 0; f < FF; ++f) s += xr[f] * wr[f];
    Z[tid] = s * dinv[b * NN + m];
}

// ---- k3: one thread per (n,o) of batch b:
//      out[b,n,o] = dinv[b,n] * sum_m A[b,n,m]*Z[m][o] + bias[o]
__global__ void k3_out(const float* __restrict__ A, const float* __restrict__ Z,
                       const float* __restrict__ dinv, const float* __restrict__ bias,
                       float* __restrict__ out, int b) {
    int tid = blockIdx.x * blockDim.x + threadIdx.x; // 0..NN*FF-1
    if (tid >= NN * FF) return;
    int n = tid >> 7, o = tid & 127;
    const float* ar = A + ((size_t)b * NN + n) * NN;
    float s = 0.f;
    for (int m = 0; m < NN; ++m) s += ar[m] * Z[m * FF + o];
    out[((size_t)b * NN + n) * FF + o] = dinv[b * NN + n] * s + bias[o];
}

extern "C" void kernel_launch(void* const* d_in, const int* in_sizes, int n_in,
                              void* d_out, int out_size, void* d_ws, size_t ws_size,
                              hipStream_t stream) {
    // Size-based binding (all element counts distinct; order-proof):
    //   adjacency 16777216, node_features 1048576, W 16384, b 128
    const float *X = nullptr, *A = nullptr, *W = nullptr, *bias = nullptr;
    for (int i = 0; i < n_in; ++i) {
        switch (in_sizes[i]) {
            case 16777216: A    = (const float*)d_in[i]; break;
            case 1048576:  X    = (const float*)d_in[i]; break;
            case 16384:    W    = (const float*)d_in[i]; break;
            case 128:      bias = (const float*)d_in[i]; break;
            default: break;
        }
    }
    float* out = (float*)d_out;

    // Gates: on failure launch nothing -> absmax == 0.7578125 signature.
    if (!X || !A || !W || !bias) return;
    if (ws_size < (size_t)WS_NEED) return;
    if (out_size != 4 * NN * FF) return;

    float* dinv = (float*)d_ws;                       // 32 KB
    float* Z    = (float*)((char*)d_ws + 32768);      // 1 MB, reused per batch

    k1_deg<<<(4 * NN) / 256, 256, 0, stream>>>(A, dinv);
    for (int b = 0; b < 4; ++b) {
        k2_z  <<<(NN * FF) / 256, 256, 0, stream>>>(X, W, dinv, Z, b);
        k3_out<<<(NN * FF) / 256, 256, 0, stream>>>(A, Z, dinv, bias, out, b);
    }
}

// Round 7
// 170.060 us; speedup vs baseline: 3.6435x; 3.6435x over previous
//
#include <hip/hip_runtime.h>

// GraphConv: out = d ∘ (A @ ((d∘X) @ W^T)) + b,  d = rsqrt(clip(rowsum(A),1e-6))
// B=4, N=2048, F=128. All I/O f32 (bisect-verified). This round: pure-f32 VALU
// with LDS tiling — reintroduces multi-wave LDS+barrier machinery but NOT
// MFMA/bf16 (still-suspect components from the failed fast path).
// k1: block-per-row degree (LDS tree). k2: Z = (dinv∘X)@W^T, f32 in ws.
// k3: out = dinv ∘ (A @ Z) + bias; 32n x 128o tile, K staged 64 at a time:
//     At[64][36] (transposed, b128-aligned reads) + Zs[64][128]; thread tile
//     4n x 4o -> per k: 2 ds_read_b128 + 16 fma.

#define NN 2048
#define FF 128

typedef __attribute__((ext_vector_type(4))) float f32x4;

// ---- k1: dinv[row] = rsqrt(max(rowsum(A),1e-6)), block per row -------------
__global__ __launch_bounds__(256) void k1_deg(const float* __restrict__ A,
                                              float* __restrict__ dinv) {
    __shared__ float red[256];
    int row = blockIdx.x;                   // 0..8191
    int t = threadIdx.x;
    const f32x4* ap = (const f32x4*)(A + (size_t)row * NN);
    f32x4 v0 = ap[t];
    f32x4 v1 = ap[t + 256];
    red[t] = v0.x + v0.y + v0.z + v0.w + v1.x + v1.y + v1.z + v1.w;
    __syncthreads();
    #pragma unroll
    for (int s = 128; s > 0; s >>= 1) {
        if (t < s) red[t] += red[t + s];
        __syncthreads();
    }
    if (t == 0) dinv[row] = rsqrtf(fmaxf(red[0], 1e-6f));
}

// ---- k2: Z[bl][m][o] = dinv[b,m] * dot(X[b,m,:], W[o,:]) -------------------
__global__ __launch_bounds__(256) void k2_z(const float* __restrict__ X,
                                            const float* __restrict__ W,
                                            const float* __restrict__ dinv,
                                            float* __restrict__ Z,
                                            int bbase, int nb) {
    int tid = blockIdx.x * 256 + threadIdx.x;      // over nb*NN*FF
    if (tid >= nb * NN * FF) return;
    int o  = tid & 127;
    int m  = (tid >> 7) & (NN - 1);
    int bl = tid >> 18;                            // NN*FF = 2^18
    int b  = bbase + bl;
    const f32x4* xr = (const f32x4*)(X + ((size_t)b * NN + m) * FF);
    const f32x4* wr = (const f32x4*)(W + (size_t)o * FF);
    float s = 0.f;
    #pragma unroll
    for (int f = 0; f < FF / 4; ++f) {
        f32x4 xv = xr[f], wv = wr[f];
        s += xv.x * wv.x + xv.y * wv.y + xv.z * wv.z + xv.w * wv.w;
    }
    Z[(size_t)tid] = s * dinv[b * NN + m];         // tid == bl*NN*FF + m*FF + o
}

// ---- k3: out[b,n,o] = dinv[b,n] * sum_m A[b,n,m]*Z[m,o] + bias[o] ----------
// grid = nbatch*64 blocks; block tile 32n x 128o, K in-block = 2048.
__global__ __launch_bounds__(256) void k3_main(const float* __restrict__ A,
                                               const float* __restrict__ Z,
                                               const float* __restrict__ dinv,
                                               const float* __restrict__ bias,
                                               float* __restrict__ out,
                                               int bbase) {
    __shared__ float At[64][36];    // transposed A tile [k][n], pad 36 (144B rows, 16B-aligned)
    __shared__ float Zs[64][128];   // Z tile [k][o]
    int blk = blockIdx.x;
    int bl  = blk >> 6;             // local batch (Z index)
    int b   = bbase + bl;           // global batch (A, dinv, out index)
    int n0  = (blk & 63) * 32;
    int t   = threadIdx.x;
    int nq  = t >> 5;               // 0..7  -> rows n0 + nq*4 .. +3
    int og  = t & 31;               // 0..31 -> cols og*4 .. +3

    const float* Ab = A + (size_t)b * NN * NN;
    const float* Zb = Z + (size_t)bl * NN * FF;

    f32x4 acc[4];
    #pragma unroll
    for (int i = 0; i < 4; ++i) acc[i] = (f32x4){0.f, 0.f, 0.f, 0.f};

    for (int k0 = 0; k0 < NN; k0 += 64) {
        // stage A[n0..n0+31][k0..k0+63] -> At[k][n] (transposed)
        #pragma unroll
        for (int j = 0; j < 2; ++j) {
            int v  = t + 256 * j;          // 0..511
            int r  = v >> 4;               // 0..31 (n within tile)
            int c4 = (v & 15) * 4;         // 0..60 (k within tile)
            f32x4 av = *(const f32x4*)(Ab + (size_t)(n0 + r) * NN + k0 + c4);
            At[c4 + 0][r] = av.x;
            At[c4 + 1][r] = av.y;
            At[c4 + 2][r] = av.z;
            At[c4 + 3][r] = av.w;
        }
        // stage Z[k0..k0+63][0..127] -> Zs
        #pragma unroll
        for (int j = 0; j < 8; ++j) {
            int v  = t + 256 * j;          // 0..2047
            int r  = v >> 5;               // 0..63
            int c4 = (v & 31) * 4;         // 0..124
            *(f32x4*)&Zs[r][c4] = *(const f32x4*)(Zb + (size_t)(k0 + r) * FF + c4);
        }
        __syncthreads();

        #pragma unroll
        for (int k = 0; k < 64; ++k) {
            f32x4 a4 = *(const f32x4*)&At[k][nq * 4];
            f32x4 z4 = *(const f32x4*)&Zs[k][og * 4];
            acc[0] += a4.x * z4;
            acc[1] += a4.y * z4;
            acc[2] += a4.z * z4;
            acc[3] += a4.w * z4;
        }
        __syncthreads();
    }

    f32x4 bv = *(const f32x4*)(bias + og * 4);
    #pragma unroll
    for (int i = 0; i < 4; ++i) {
        int n = n0 + nq * 4 + i;
        float dv = dinv[b * NN + n];
        f32x4 r;
        r.x = acc[i].x * dv + bv.x;
        r.y = acc[i].y * dv + bv.y;
        r.z = acc[i].z * dv + bv.z;
        r.w = acc[i].w * dv + bv.w;
        *(f32x4*)(out + ((size_t)b * NN + n) * FF + og * 4) = r;
    }
}

extern "C" void kernel_launch(void* const* d_in, const int* in_sizes, int n_in,
                              void* d_out, int out_size, void* d_ws, size_t ws_size,
                              hipStream_t stream) {
    // Bind inputs by element count (all distinct; order-proof):
    const float *X = nullptr, *A = nullptr, *W = nullptr, *bias = nullptr;
    for (int i = 0; i < n_in; ++i) {
        switch (in_sizes[i]) {
            case 16777216: A    = (const float*)d_in[i]; break;  // [4,2048,2048]
            case 1048576:  X    = (const float*)d_in[i]; break;  // [4,2048,128]
            case 16384:    W    = (const float*)d_in[i]; break;  // [128,128]
            case 128:      bias = (const float*)d_in[i]; break;  // [128]
            default: break;
        }
    }
    float* out = (float*)d_out;
    if (!X || !A || !W || !bias) return;            // signature: absmax 0.7578125
    if (out_size != 4 * NN * FF) return;

    const size_t need_min  = 32768u + (size_t)NN * FF * 4;       // dinv + Z(1 batch)
    const size_t need_full = 32768u + (size_t)4 * NN * FF * 4;   // dinv + Z(4 batches)
    if (ws_size < need_min) return;

    float* dinv = (float*)d_ws;                     // 32 KB
    float* Z    = (float*)((char*)d_ws + 32768);    // 1 or 4 MB f32

    k1_deg<<<4 * NN, 256, 0, stream>>>(A, dinv);

    if (ws_size >= need_full) {
        k2_z<<<(4 * NN * FF) / 256, 256, 0, stream>>>(X, W, dinv, Z, 0, 4);
        k3_main<<<4 * 64, 256, 0, stream>>>(A, Z, dinv, bias, out, 0);
    } else {
        for (int b = 0; b < 4; ++b) {               // low-ws fallback (deterministic)
            k2_z<<<(NN * FF) / 256, 256, 0, stream>>>(X, W, dinv, Z, b, 1);
            k3_main<<<64, 256, 0, stream>>>(A, Z, dinv, bias, out, b);
        }
    }
}

// Round 9
// 155.758 us; speedup vs baseline: 3.9781x; 1.0918x over previous
//
#include <hip/hip_runtime.h>

// GraphConv: out = d ∘ (A @ ((d∘X) @ W^T)) + b,  d = rsqrt(clip(rowsum(A),1e-6))
// B=4, N=2048, F=128. All f32 I/O, size-based binding (R6/R7-verified).
// BISECT R9: R8 minus its MFMA k_main only. k1/k2_zt VERBATIM from R8
// (bf16 Zt + f2bf still under test); k3 is f32-VALU consuming the same Zt.
// PASS => MFMA block in k_main convicted. FAIL ~33 => f2bf/Zt path convicted.

#define NN 2048
#define FF 128
#define WS_NEED (32768u + 4u * 128u * 2048u * 2u)   // dinv(32KB)+Zt(2MB)

typedef __attribute__((ext_vector_type(4))) float f32x4;
typedef __attribute__((ext_vector_type(8))) short short8;

__device__ inline float bf2f(unsigned short h) {
    return __builtin_bit_cast(float, ((unsigned)h) << 16);
}
// f32 -> bf16 round-to-nearest-even (finite inputs only)
__device__ inline unsigned short f2bf(float f) {
    unsigned u = __builtin_bit_cast(unsigned, f);
    u = (u + 0x7fffu + ((u >> 16) & 1u)) >> 16;
    return (unsigned short)u;
}

// ---- k1: dinv[row] = rsqrt(max(rowsum(A),1e-6))  [R8 verbatim] -------------
__global__ __launch_bounds__(256) void k1_deg(const float* __restrict__ A,
                                              float* __restrict__ dinv) {
    __shared__ float red[256];
    int row = blockIdx.x;
    int t = threadIdx.x;
    const f32x4* ap = (const f32x4*)(A + (size_t)row * NN);
    f32x4 v0 = ap[t];
    f32x4 v1 = ap[t + 256];
    red[t] = v0.x + v0.y + v0.z + v0.w + v1.x + v1.y + v1.z + v1.w;
    __syncthreads();
    #pragma unroll
    for (int s = 128; s > 0; s >>= 1) {
        if (t < s) red[t] += red[t + s];
        __syncthreads();
    }
    if (t == 0) dinv[row] = rsqrtf(fmaxf(red[0], 1e-6f));
}

// ---- k2: Zt[b][o][m] = bf16(dinv[b,m] * dot(X[b,m,:], W[o,:]))  [R8 verbatim]
__global__ __launch_bounds__(256) void k2_zt(const float* __restrict__ X,
                                             const float* __restrict__ W,
                                             const float* __restrict__ dinv,
                                             unsigned short* __restrict__ Zt) {
    int blk = blockIdx.x;
    int b  = blk >> 6;                      // 0..3
    int mc = (blk >> 3) & 7;                // 0..7
    int oc = blk & 7;                       // 0..7
    int m  = mc * 256 + threadIdx.x;        // 0..2047

    float acc[16];
    #pragma unroll
    for (int j = 0; j < 16; ++j) acc[j] = 0.f;

    const f32x4* xr = (const f32x4*)(X + ((size_t)b * NN + m) * FF);
    for (int f4 = 0; f4 < FF / 4; ++f4) {
        f32x4 xv = xr[f4];
        #pragma unroll
        for (int j = 0; j < 16; ++j) {
            f32x4 wv = *(const f32x4*)(W + (size_t)(oc * 16 + j) * FF + f4 * 4);
            acc[j] += xv.x * wv.x + xv.y * wv.y + xv.z * wv.z + xv.w * wv.w;
        }
    }
    float dv = dinv[b * NN + m];
    #pragma unroll
    for (int j = 0; j < 16; ++j)
        Zt[((size_t)b * FF + oc * 16 + j) * NN + m] = f2bf(acc[j] * dv);
}

// ---- k3: out[b,n,o] = dinv[b,n] * sum_m A[b,n,m]*Z[m,o] + bias[o] ----------
// f32 VALU, consumes R8's transposed bf16 Zt. 512 blocks (2/CU), 16n x 128o
// tile, K chunked by 64. Zt chunk transposed into Zs[m][o] during staging
// (pad 131 -> 2-way store conflicts only); o interleaved mod 32 per thread
// -> conflict-free b32 reads. At[64][18] staged transposed for broadcast reads.
__global__ __launch_bounds__(256) void k3_f32(const float* __restrict__ A,
                                              const unsigned short* __restrict__ Zt,
                                              const float* __restrict__ dinv,
                                              const float* __restrict__ bias,
                                              float* __restrict__ out) {
    __shared__ float At[64][18];
    __shared__ float Zs[64][131];
    int blk = blockIdx.x;            // 0..511
    int b   = blk >> 7;              // 0..3
    int n0  = (blk & 127) * 16;      // 0..2032
    int t   = threadIdx.x;
    int nq  = t >> 5;                // 0..7 -> rows nq*2, nq*2+1
    int og  = t & 31;                // 0..31 -> cols og, og+32, og+64, og+96

    const float* Ab = A + (size_t)b * NN * NN;
    const unsigned short* Zb = Zt + (size_t)b * FF * NN;

    float acc[2][4] = {{0.f,0.f,0.f,0.f},{0.f,0.f,0.f,0.f}};

    for (int k0 = 0; k0 < NN; k0 += 64) {
        __syncthreads();                       // protect previous iter's reads
        {   // stage A[n0..n0+15][k0..k0+63] -> At[k][n]
            int r  = t >> 4;                   // 0..15
            int c4 = (t & 15) * 4;             // 0..60
            f32x4 av = *(const f32x4*)(Ab + (size_t)(n0 + r) * NN + k0 + c4);
            At[c4+0][r] = av.x; At[c4+1][r] = av.y;
            At[c4+2][r] = av.z; At[c4+3][r] = av.w;
        }
        // stage Zt[o][k0..k0+63] -> Zs[m][o]  (128 o x 64 m, bf16->f32)
        #pragma unroll
        for (int j = 0; j < 4; ++j) {
            int idx = t + 256 * j;             // 0..1023
            int o   = idx >> 3;                // 0..127
            int m8  = (idx & 7) * 8;           // 0..56
            short8 zv = *(const short8*)(Zb + (size_t)o * NN + k0 + m8);
            #pragma unroll
            for (int i = 0; i < 8; ++i)
                Zs[m8 + i][o] = bf2f((unsigned short)zv[i]);
        }
        __syncthreads();

        #pragma unroll 4
        for (int k = 0; k < 64; ++k) {
            float a0 = At[k][nq * 2 + 0];
            float a1 = At[k][nq * 2 + 1];
            #pragma unroll
            for (int c = 0; c < 4; ++c) {
                float z = Zs[k][og + 32 * c];
                acc[0][c] += a0 * z;
                acc[1][c] += a1 * z;
            }
        }
    }

    #pragma unroll
    for (int i = 0; i < 2; ++i) {
        int n = n0 + nq * 2 + i;
        float dv = dinv[b * NN + n];
        #pragma unroll
        for (int c = 0; c < 4; ++c) {
            int o = og + 32 * c;
            out[((size_t)b * NN + n) * FF + o] = acc[i][c] * dv + bias[o];
        }
    }
}

extern "C" void kernel_launch(void* const* d_in, const int* in_sizes, int n_in,
                              void* d_out, int out_size, void* d_ws, size_t ws_size,
                              hipStream_t stream) {
    // Bind inputs by element count (all distinct; order-proof):
    const float *X = nullptr, *A = nullptr, *W = nullptr, *bias = nullptr;
    for (int i = 0; i < n_in; ++i) {
        switch (in_sizes[i]) {
            case 16777216: A    = (const float*)d_in[i]; break;  // [4,2048,2048]
            case 1048576:  X    = (const float*)d_in[i]; break;  // [4,2048,128]
            case 16384:    W    = (const float*)d_in[i]; break;  // [128,128]
            case 128:      bias = (const float*)d_in[i]; break;  // [128]
            default: break;
        }
    }
    float* out = (float*)d_out;
    if (!X || !A || !W || !bias) return;        // signature: absmax 0.7578125
    if (out_size != 4 * NN * FF) return;
    if (ws_size < (size_t)WS_NEED) return;

    float* dinv        = (float*)d_ws;                            // 32 KB
    unsigned short* Zt = (unsigned short*)((char*)d_ws + 32768);  // 2 MB bf16

    k1_deg<<<4 * NN, 256, 0, stream>>>(A, dinv);
    k2_zt<<<256, 256, 0, stream>>>(X, W, dinv, Zt);
    k3_f32<<<512, 256, 0, stream>>>(A, Zt, dinv, bias, out);
}

// Round 10
// 89.247 us; speedup vs baseline: 6.9427x; 1.7452x over previous
//
#include <hip/hip_runtime.h>

// GraphConv: out = d ∘ (A @ ((d∘X) @ W^T)) + b,  d = rsqrt(clip(rowsum(A),1e-6))
// B=4, N=2048, F=128. All f32 I/O, size-based binding (R6-verified).
// R9 bisect: k1/k2_zt/f32-consumption all verified-correct; old MFMA k_main
// convicted. THIS ROUND: k3 rebuilt as MFMA in the m91-m103 verified-ladder
// form (LDS-staged operands, contiguous 16B fragment reads, no split-K,
// simple per-wave epilogue). k1/k2_zt VERBATIM from R9.

#define NN 2048
#define FF 128
#define WS_NEED (32768u + 4u * 128u * 2048u * 2u)   // dinv(32KB)+Zt(2MB)

typedef __attribute__((ext_vector_type(4))) float f32x4;
typedef __attribute__((ext_vector_type(8))) short short8;

__device__ inline float bf2f(unsigned short h) {
    return __builtin_bit_cast(float, ((unsigned)h) << 16);
}
// f32 -> bf16 round-to-nearest-even (finite inputs only)
__device__ inline unsigned short f2bf(float f) {
    unsigned u = __builtin_bit_cast(unsigned, f);
    u = (u + 0x7fffu + ((u >> 16) & 1u)) >> 16;
    return (unsigned short)u;
}

__device__ inline short8 cvt8(f32x4 a, f32x4 b) {
    short8 r;
    r[0] = (short)f2bf(a.x); r[1] = (short)f2bf(a.y);
    r[2] = (short)f2bf(a.z); r[3] = (short)f2bf(a.w);
    r[4] = (short)f2bf(b.x); r[5] = (short)f2bf(b.y);
    r[6] = (short)f2bf(b.z); r[7] = (short)f2bf(b.w);
    return r;
}

// ---- k1: dinv[row] = rsqrt(max(rowsum(A),1e-6))  [R9 verbatim] -------------
__global__ __launch_bounds__(256) void k1_deg(const float* __restrict__ A,
                                              float* __restrict__ dinv) {
    __shared__ float red[256];
    int row = blockIdx.x;
    int t = threadIdx.x;
    const f32x4* ap = (const f32x4*)(A + (size_t)row * NN);
    f32x4 v0 = ap[t];
    f32x4 v1 = ap[t + 256];
    red[t] = v0.x + v0.y + v0.z + v0.w + v1.x + v1.y + v1.z + v1.w;
    __syncthreads();
    #pragma unroll
    for (int s = 128; s > 0; s >>= 1) {
        if (t < s) red[t] += red[t + s];
        __syncthreads();
    }
    if (t == 0) dinv[row] = rsqrtf(fmaxf(red[0], 1e-6f));
}

// ---- k2: Zt[b][o][m] = bf16(dinv[b,m] * dot(X[b,m,:], W[o,:]))  [R9 verbatim]
__global__ __launch_bounds__(256) void k2_zt(const float* __restrict__ X,
                                             const float* __restrict__ W,
                                             const float* __restrict__ dinv,
                                             unsigned short* __restrict__ Zt) {
    int blk = blockIdx.x;
    int b  = blk >> 6;                      // 0..3
    int mc = (blk >> 3) & 7;                // 0..7
    int oc = blk & 7;                       // 0..7
    int m  = mc * 256 + threadIdx.x;        // 0..2047

    float acc[16];
    #pragma unroll
    for (int j = 0; j < 16; ++j) acc[j] = 0.f;

    const f32x4* xr = (const f32x4*)(X + ((size_t)b * NN + m) * FF);
    for (int f4 = 0; f4 < FF / 4; ++f4) {
        f32x4 xv = xr[f4];
        #pragma unroll
        for (int j = 0; j < 16; ++j) {
            f32x4 wv = *(const f32x4*)(W + (size_t)(oc * 16 + j) * FF + f4 * 4);
            acc[j] += xv.x * wv.x + xv.y * wv.y + xv.z * wv.z + xv.w * wv.w;
        }
    }
    float dv = dinv[b * NN + m];
    #pragma unroll
    for (int j = 0; j < 16; ++j)
        Zt[((size_t)b * FF + oc * 16 + j) * NN + m] = f2bf(acc[j] * dv);
}

// ---- k3: out[b,n,o] = dinv[b,n] * sum_m A[b,n,m]*Z[m,o] + bias[o] ----------
// MFMA in the verified-ladder form: both operands LDS-staged, fragments are
// contiguous 16B LDS reads, no split-K. 256 blocks = b(4) x ntile(32) x
// ohalf(2); tile 64n x 64o; 4 waves, wave w owns rows [w*16, w*16+16).
// Rows padded to 72 shorts (144B): fragment reads are 2-way bank-aliased
// (free per m136). A-operand: row=lane&15, k=(lane>>4)*8+j; B-operand:
// col=lane&15, same k; C/D: col=lane&15, row=(lane>>4)*4+r (m89-verified).
__global__ __launch_bounds__(256) void k3_mfma(const float* __restrict__ A,
                                               const unsigned short* __restrict__ Zt,
                                               const float* __restrict__ dinv,
                                               const float* __restrict__ bias,
                                               float* __restrict__ out) {
    __shared__ unsigned short As[64][72];   // A tile  [n][k], bf16
    __shared__ unsigned short Zs[64][72];   // Z^T tile [o][k], bf16
    int blk = blockIdx.x;                   // 0..255
    int b   = blk >> 6;                     // 0..3
    int n0  = ((blk >> 1) & 31) * 64;       // 0..1984
    int o0  = (blk & 1) * 64;               // 0 or 64
    int t   = threadIdx.x;
    int w   = t >> 6, lane = t & 63;
    int l15 = lane & 15, kgrp = (lane >> 4) * 8;

    const float* Ab = A + (size_t)b * NN * NN;
    const unsigned short* Zb = Zt + (size_t)b * FF * NN;

    f32x4 acc[4];
    #pragma unroll
    for (int i = 0; i < 4; ++i) acc[i] = (f32x4){0.f, 0.f, 0.f, 0.f};

    int sr = t >> 2;                        // staging row 0..63
    int sc = (t & 3) * 16;                  // staging col 0,16,32,48

    for (int k0 = 0; k0 < NN; k0 += 64) {
        __syncthreads();                    // protect previous iter's reads
        {   // stage A[n0+sr][k0+sc .. +15] -> As (f32 -> bf16)
            const float* src = Ab + (size_t)(n0 + sr) * NN + k0 + sc;
            f32x4 a0 = *(const f32x4*)(src);
            f32x4 a1 = *(const f32x4*)(src + 4);
            f32x4 a2 = *(const f32x4*)(src + 8);
            f32x4 a3 = *(const f32x4*)(src + 12);
            *(short8*)&As[sr][sc]     = cvt8(a0, a1);
            *(short8*)&As[sr][sc + 8] = cvt8(a2, a3);
        }
        {   // stage Zt[o0+sr][k0+sc .. +15] -> Zs (already bf16)
            const unsigned short* src = Zb + (size_t)(o0 + sr) * NN + k0 + sc;
            *(short8*)&Zs[sr][sc]     = *(const short8*)(src);
            *(short8*)&Zs[sr][sc + 8] = *(const short8*)(src + 8);
        }
        __syncthreads();

        #pragma unroll
        for (int ks = 0; ks < 64; ks += 32) {
            short8 af = *(const short8*)&As[w * 16 + l15][ks + kgrp];
            #pragma unroll
            for (int tt = 0; tt < 4; ++tt) {
                short8 bf = *(const short8*)&Zs[tt * 16 + l15][ks + kgrp];
                acc[tt] = __builtin_amdgcn_mfma_f32_16x16x32_bf16(af, bf, acc[tt], 0, 0, 0);
            }
        }
    }

    int drow = (lane >> 4) * 4;
    #pragma unroll
    for (int tt = 0; tt < 4; ++tt) {
        int o = o0 + tt * 16 + l15;
        float bv = bias[o];
        #pragma unroll
        for (int r = 0; r < 4; ++r) {
            int n = n0 + w * 16 + drow + r;
            float dv = dinv[b * NN + n];
            out[((size_t)b * NN + n) * FF + o] = dv * acc[tt][r] + bv;
        }
    }
}

extern "C" void kernel_launch(void* const* d_in, const int* in_sizes, int n_in,
                              void* d_out, int out_size, void* d_ws, size_t ws_size,
                              hipStream_t stream) {
    // Bind inputs by element count (all distinct; order-proof):
    const float *X = nullptr, *A = nullptr, *W = nullptr, *bias = nullptr;
    for (int i = 0; i < n_in; ++i) {
        switch (in_sizes[i]) {
            case 16777216: A    = (const float*)d_in[i]; break;  // [4,2048,2048]
            case 1048576:  X    = (const float*)d_in[i]; break;  // [4,2048,128]
            case 16384:    W    = (const float*)d_in[i]; break;  // [128,128]
            case 128:      bias = (const float*)d_in[i]; break;  // [128]
            default: break;
        }
    }
    float* out = (float*)d_out;
    if (!X || !A || !W || !bias) return;        // signature: absmax 0.7578125
    if (out_size != 4 * NN * FF) return;
    if (ws_size < (size_t)WS_NEED) return;

    float* dinv        = (float*)d_ws;                            // 32 KB
    unsigned short* Zt = (unsigned short*)((char*)d_ws + 32768);  // 2 MB bf16

    k1_deg<<<4 * NN, 256, 0, stream>>>(A, dinv);
    k2_zt<<<256, 256, 0, stream>>>(X, W, dinv, Zt);
    k3_mfma<<<256, 256, 0, stream>>>(A, Zt, dinv, bias, out);
}

// Round 11
// 55.030 us; speedup vs baseline: 11.2596x; 1.6218x over previous
//
#include <hip/hip_runtime.h>

// GraphConv: out = d ∘ (A @ ((d∘X) @ W^T)) + b,  d = rsqrt(clip(rowsum(A),1e-6))
// B=4, N=2048, F=128. All f32 I/O, size-based binding (R6-verified).
// R10 passed (MFMA, verified-ladder form). R11 = same math, performance pass:
//  k1: unchanged (block-per-row degree).
//  k2: W staged in LDS (broadcast reads) instead of per-thread global loads.
//  k3: 16n x 128o tiles, grid 512 (2 blocks/CU), double-buffered LDS with
//      T14 async-stage split (issue loads -> MFMA -> ds_write -> barrier).
//      MFMA fragment/epilogue conventions BYTE-IDENTICAL to R10's verified k3.

#define NN 2048
#define FF 128
#define WS_NEED (32768u + 4u * 128u * 2048u * 2u)   // dinv(32KB)+Zt(2MB)

typedef __attribute__((ext_vector_type(4))) float f32x4;
typedef __attribute__((ext_vector_type(8))) short short8;

__device__ inline float bf2f(unsigned short h) {
    return __builtin_bit_cast(float, ((unsigned)h) << 16);
}
// f32 -> bf16 round-to-nearest-even (finite inputs only)
__device__ inline unsigned short f2bf(float f) {
    unsigned u = __builtin_bit_cast(unsigned, f);
    u = (u + 0x7fffu + ((u >> 16) & 1u)) >> 16;
    return (unsigned short)u;
}

__device__ inline short8 cvt8(f32x4 a, f32x4 b) {
    short8 r;
    r[0] = (short)f2bf(a.x); r[1] = (short)f2bf(a.y);
    r[2] = (short)f2bf(a.z); r[3] = (short)f2bf(a.w);
    r[4] = (short)f2bf(b.x); r[5] = (short)f2bf(b.y);
    r[6] = (short)f2bf(b.z); r[7] = (short)f2bf(b.w);
    return r;
}

// ---- k1: dinv[row] = rsqrt(max(rowsum(A),1e-6))  [R10 verbatim] ------------
__global__ __launch_bounds__(256) void k1_deg(const float* __restrict__ A,
                                              float* __restrict__ dinv) {
    __shared__ float red[256];
    int row = blockIdx.x;
    int t = threadIdx.x;
    const f32x4* ap = (const f32x4*)(A + (size_t)row * NN);
    f32x4 v0 = ap[t];
    f32x4 v1 = ap[t + 256];
    red[t] = v0.x + v0.y + v0.z + v0.w + v1.x + v1.y + v1.z + v1.w;
    __syncthreads();
    #pragma unroll
    for (int s = 128; s > 0; s >>= 1) {
        if (t < s) red[t] += red[t + s];
        __syncthreads();
    }
    if (t == 0) dinv[row] = rsqrtf(fmaxf(red[0], 1e-6f));
}

// ---- k2: Zt[b][o][m] = bf16(dinv[b,m] * dot(X[b,m,:], W[o,:])) -------------
// Same math/accumulation order as R10's k2_zt; W now staged once into LDS
// (64 KB f32) and read via wave-uniform broadcast (conflict-free).
__global__ __launch_bounds__(256) void k2_zt(const float* __restrict__ X,
                                             const float* __restrict__ W,
                                             const float* __restrict__ dinv,
                                             unsigned short* __restrict__ Zt) {
    __shared__ float Ws[FF * FF];           // 64 KB
    int blk = blockIdx.x;
    int b  = blk >> 6;                      // 0..3
    int mc = (blk >> 3) & 7;                // 0..7
    int oc = blk & 7;                       // 0..7
    int t  = threadIdx.x;
    int m  = mc * 256 + t;                  // 0..2047

    {   // stage all of W: 16384 f32 = 4096 f32x4; 256 thr x 16
        f32x4* wd = (f32x4*)Ws;
        const f32x4* wsrc = (const f32x4*)W;
        #pragma unroll
        for (int j = 0; j < 16; ++j) wd[t + 256 * j] = wsrc[t + 256 * j];
    }
    __syncthreads();

    float acc[16];
    #pragma unroll
    for (int j = 0; j < 16; ++j) acc[j] = 0.f;

    const f32x4* xr = (const f32x4*)(X + ((size_t)b * NN + m) * FF);
    for (int f4 = 0; f4 < FF / 4; ++f4) {
        f32x4 xv = xr[f4];
        #pragma unroll
        for (int j = 0; j < 16; ++j) {
            f32x4 wv = *(const f32x4*)&Ws[(oc * 16 + j) * FF + f4 * 4];
            acc[j] += xv.x * wv.x + xv.y * wv.y + xv.z * wv.z + xv.w * wv.w;
        }
    }
    float dv = dinv[b * NN + m];
    #pragma unroll
    for (int j = 0; j < 16; ++j)
        Zt[((size_t)b * FF + oc * 16 + j) * NN + m] = f2bf(acc[j] * dv);
}

// ---- k3: out[b,n,o] = dinv[b,n] * sum_m A[b,n,m]*Z[m,o] + bias[o] ----------
// 512 blocks = b(4) x ntile(128); tile 16n x 128o; 4 waves, wave w owns
// o-range [w*32, w*32+32) (2 MFMA tiles). Double-buffered LDS; per iter:
// issue next-tile global loads (regs) -> MFMA on cur -> ds_write next ->
// one barrier. Fragment conventions identical to R10 (verified).
__global__ __launch_bounds__(256) void k3_mfma(const float* __restrict__ A,
                                               const unsigned short* __restrict__ Zt,
                                               const float* __restrict__ dinv,
                                               const float* __restrict__ bias,
                                               float* __restrict__ out) {
    __shared__ unsigned short As[2][16][72];    // A tile  [n][k] bf16
    __shared__ unsigned short Zs[2][128][72];   // Z^T tile [o][k] bf16
    int blk = blockIdx.x;                   // 0..511
    int b   = blk >> 7;                     // 0..3
    int n0  = (blk & 127) * 16;             // 0..2032
    int t   = threadIdx.x;
    int w   = t >> 6, lane = t & 63;
    int l15 = lane & 15, kgrp = (lane >> 4) * 8;

    const float* Ab = A + (size_t)b * NN * NN;
    const unsigned short* Zb = Zt + (size_t)b * FF * NN;

    // staging assignments
    int ar = t >> 3;                        // (t<128): 0..15
    int ac = (t & 7) * 8;                   // 0..56
    int zo = t >> 1;                        // 0..127
    int zk = (t & 1) * 32;                  // 0 or 32

    f32x4 acc[2];
    acc[0] = (f32x4){0.f, 0.f, 0.f, 0.f};
    acc[1] = (f32x4){0.f, 0.f, 0.f, 0.f};

    f32x4 a0, a1;                           // A staging regs (t<128)
    short8 z0, z1, z2, z3;                  // Zt staging regs

    #define LOADT(k0)                                                        \
        do {                                                                 \
            if (t < 128) {                                                   \
                const float* asrc = Ab + (size_t)(n0 + ar) * NN + (k0) + ac; \
                a0 = *(const f32x4*)asrc;                                    \
                a1 = *(const f32x4*)(asrc + 4);                              \
            }                                                                \
            const unsigned short* zsrc = Zb + (size_t)zo * NN + (k0) + zk;   \
            z0 = *(const short8*)(zsrc);                                     \
            z1 = *(const short8*)(zsrc + 8);                                 \
            z2 = *(const short8*)(zsrc + 16);                                \
            z3 = *(const short8*)(zsrc + 24);                                \
        } while (0)

    #define WRITET(buf)                                                      \
        do {                                                                 \
            if (t < 128) *(short8*)&As[buf][ar][ac] = cvt8(a0, a1);          \
            *(short8*)&Zs[buf][zo][zk]      = z0;                            \
            *(short8*)&Zs[buf][zo][zk + 8]  = z1;                            \
            *(short8*)&Zs[buf][zo][zk + 16] = z2;                            \
            *(short8*)&Zs[buf][zo][zk + 24] = z3;                            \
        } while (0)

    LOADT(0);
    WRITET(0);
    __syncthreads();

    for (int it = 0; it < NN / 64; ++it) {
        int cur = it & 1;
        if (it + 1 < NN / 64) LOADT((it + 1) * 64);     // issue early (T14)
        #pragma unroll
        for (int ks = 0; ks < 64; ks += 32) {
            short8 af = *(const short8*)&As[cur][l15][ks + kgrp];
            #pragma unroll
            for (int tt = 0; tt < 2; ++tt) {
                short8 bf = *(const short8*)&Zs[cur][w * 32 + tt * 16 + l15][ks + kgrp];
                acc[tt] = __builtin_amdgcn_mfma_f32_16x16x32_bf16(af, bf, acc[tt], 0, 0, 0);
            }
        }
        if (it + 1 < NN / 64) WRITET(cur ^ 1);          // write late (T14)
        __syncthreads();
    }

    int drow = (lane >> 4) * 4;
    #pragma unroll
    for (int tt = 0; tt < 2; ++tt) {
        int o = w * 32 + tt * 16 + l15;
        float bv = bias[o];
        #pragma unroll
        for (int r = 0; r < 4; ++r) {
            int n = n0 + drow + r;
            float dv = dinv[b * NN + n];
            out[((size_t)b * NN + n) * FF + o] = dv * acc[tt][r] + bv;
        }
    }
    #undef LOADT
    #undef WRITET
}

extern "C" void kernel_launch(void* const* d_in, const int* in_sizes, int n_in,
                              void* d_out, int out_size, void* d_ws, size_t ws_size,
                              hipStream_t stream) {
    // Bind inputs by element count (all distinct; order-proof):
    const float *X = nullptr, *A = nullptr, *W = nullptr, *bias = nullptr;
    for (int i = 0; i < n_in; ++i) {
        switch (in_sizes[i]) {
            case 16777216: A    = (const float*)d_in[i]; break;  // [4,2048,2048]
            case 1048576:  X    = (const float*)d_in[i]; break;  // [4,2048,128]
            case 16384:    W    = (const float*)d_in[i]; break;  // [128,128]
            case 128:      bias = (const float*)d_in[i]; break;  // [128]
            default: break;
        }
    }
    float* out = (float*)d_out;
    if (!X || !A || !W || !bias) return;        // signature: absmax 0.7578125
    if (out_size != 4 * NN * FF) return;
    if (ws_size < (size_t)WS_NEED) return;

    float* dinv        = (float*)d_ws;                            // 32 KB
    unsigned short* Zt = (unsigned short*)((char*)d_ws + 32768);  // 2 MB bf16

    k1_deg<<<4 * NN, 256, 0, stream>>>(A, dinv);
    k2_zt<<<256, 256, 0, stream>>>(X, W, dinv, Zt);
    k3_mfma<<<512, 256, 0, stream>>>(A, Zt, dinv, bias, out);
}

// Round 12
// 52.230 us; speedup vs baseline: 11.8633x; 1.0536x over previous
//
#include <hip/hip_runtime.h>

// GraphConv: out = d ∘ (A @ ((d∘X) @ W^T)) + b,  d = rsqrt(clip(rowsum(A),1e-6))
// B=4, N=2048, F=128. All f32 I/O, size-based binding (R6-verified).
// R11: 55 µs (k1~11, k2~4, k3~38). R12: k3 depth-2 prefetch — two named
// register sets (no runtime-indexed reg arrays), loads issued 2 tiles ahead,
// one barrier/iter. MFMA fragment/epilogue conventions IDENTICAL to R10/R11
// (verified). k1/k2 unchanged from R11.

#define NN 2048
#define FF 128
#define WS_NEED (32768u + 4u * 128u * 2048u * 2u)   // dinv(32KB)+Zt(2MB)

typedef __attribute__((ext_vector_type(4))) float f32x4;
typedef __attribute__((ext_vector_type(8))) short short8;

__device__ inline float bf2f(unsigned short h) {
    return __builtin_bit_cast(float, ((unsigned)h) << 16);
}
// f32 -> bf16 round-to-nearest-even (finite inputs only)
__device__ inline unsigned short f2bf(float f) {
    unsigned u = __builtin_bit_cast(unsigned, f);
    u = (u + 0x7fffu + ((u >> 16) & 1u)) >> 16;
    return (unsigned short)u;
}

__device__ inline short8 cvt8(f32x4 a, f32x4 b) {
    short8 r;
    r[0] = (short)f2bf(a.x); r[1] = (short)f2bf(a.y);
    r[2] = (short)f2bf(a.z); r[3] = (short)f2bf(a.w);
    r[4] = (short)f2bf(b.x); r[5] = (short)f2bf(b.y);
    r[6] = (short)f2bf(b.z); r[7] = (short)f2bf(b.w);
    return r;
}

// ---- k1: dinv[row] = rsqrt(max(rowsum(A),1e-6))  [R11 verbatim] ------------
__global__ __launch_bounds__(256) void k1_deg(const float* __restrict__ A,
                                              float* __restrict__ dinv) {
    __shared__ float red[256];
    int row = blockIdx.x;
    int t = threadIdx.x;
    const f32x4* ap = (const f32x4*)(A + (size_t)row * NN);
    f32x4 v0 = ap[t];
    f32x4 v1 = ap[t + 256];
    red[t] = v0.x + v0.y + v0.z + v0.w + v1.x + v1.y + v1.z + v1.w;
    __syncthreads();
    #pragma unroll
    for (int s = 128; s > 0; s >>= 1) {
        if (t < s) red[t] += red[t + s];
        __syncthreads();
    }
    if (t == 0) dinv[row] = rsqrtf(fmaxf(red[0], 1e-6f));
}

// ---- k2: Zt[b][o][m] = bf16(dinv[b,m] * dot(X[b,m,:], W[o,:]))  [R11 verbatim]
__global__ __launch_bounds__(256) void k2_zt(const float* __restrict__ X,
                                             const float* __restrict__ W,
                                             const float* __restrict__ dinv,
                                             unsigned short* __restrict__ Zt) {
    __shared__ float Ws[FF * FF];           // 64 KB
    int blk = blockIdx.x;
    int b  = blk >> 6;                      // 0..3
    int mc = (blk >> 3) & 7;                // 0..7
    int oc = blk & 7;                       // 0..7
    int t  = threadIdx.x;
    int m  = mc * 256 + t;                  // 0..2047

    {   // stage all of W: 16384 f32 = 4096 f32x4; 256 thr x 16
        f32x4* wd = (f32x4*)Ws;
        const f32x4* wsrc = (const f32x4*)W;
        #pragma unroll
        for (int j = 0; j < 16; ++j) wd[t + 256 * j] = wsrc[t + 256 * j];
    }
    __syncthreads();

    float acc[16];
    #pragma unroll
    for (int j = 0; j < 16; ++j) acc[j] = 0.f;

    const f32x4* xr = (const f32x4*)(X + ((size_t)b * NN + m) * FF);
    for (int f4 = 0; f4 < FF / 4; ++f4) {
        f32x4 xv = xr[f4];
        #pragma unroll
        for (int j = 0; j < 16; ++j) {
            f32x4 wv = *(const f32x4*)&Ws[(oc * 16 + j) * FF + f4 * 4];
            acc[j] += xv.x * wv.x + xv.y * wv.y + xv.z * wv.z + xv.w * wv.w;
        }
    }
    float dv = dinv[b * NN + m];
    #pragma unroll
    for (int j = 0; j < 16; ++j)
        Zt[((size_t)b * FF + oc * 16 + j) * NN + m] = f2bf(acc[j] * dv);
}

// ---- k3: out[b,n,o] = dinv[b,n] * sum_m A[b,n,m]*Z[m,o] + bias[o] ----------
// 512 blocks = b(4) x ntile(128); tile 16n x 128o; 4 waves, wave w owns
// o-range [w*32, +32). Double-buffered LDS, DEPTH-2 register prefetch:
// iter it: issue loads(it+2) into set B; MFMA on buf[it&1]; LDS-write set A
// (holding it+1) into buf[(it+1)&1]; swap roles (unrolled x2, named sets).
// One barrier per iter. Fragment conventions identical to R10/R11 (verified).
__global__ __launch_bounds__(256) void k3_mfma(const float* __restrict__ A,
                                               const unsigned short* __restrict__ Zt,
                                               const float* __restrict__ dinv,
                                               const float* __restrict__ bias,
                                               float* __restrict__ out) {
    __shared__ unsigned short As[2][16][72];    // A tile  [n][k] bf16
    __shared__ unsigned short Zs[2][128][72];   // Z^T tile [o][k] bf16
    int blk = blockIdx.x;                   // 0..511
    int b   = blk >> 7;                     // 0..3
    int n0  = (blk & 127) * 16;             // 0..2032
    int t   = threadIdx.x;
    int w   = t >> 6, lane = t & 63;
    int l15 = lane & 15, kgrp = (lane >> 4) * 8;

    const float* Ab = A + (size_t)b * NN * NN;
    const unsigned short* Zb = Zt + (size_t)b * FF * NN;

    // staging assignments
    int ar = t >> 3;                        // (t<128): 0..15
    int ac = (t & 7) * 8;                   // 0..56
    int zo = t >> 1;                        // 0..127
    int zk = (t & 1) * 32;                  // 0 or 32

    f32x4 acc[2];
    acc[0] = (f32x4){0.f, 0.f, 0.f, 0.f};
    acc[1] = (f32x4){0.f, 0.f, 0.f, 0.f};

    // two named register staging sets (rule #20: no runtime-indexed reg arrays)
    f32x4 pa0, pa1;  short8 pz0, pz1, pz2, pz3;   // set P
    f32x4 qa0, qa1;  short8 qz0, qz1, qz2, qz3;   // set Q

    #define LOADT(A0, A1, Z0, Z1, Z2, Z3, k0)                                \
        do {                                                                 \
            if (t < 128) {                                                   \
                const float* asrc = Ab + (size_t)(n0 + ar) * NN + (k0) + ac; \
                A0 = *(const f32x4*)asrc;                                    \
                A1 = *(const f32x4*)(asrc + 4);                              \
            }                                                                \
            const unsigned short* zsrc = Zb + (size_t)zo * NN + (k0) + zk;   \
            Z0 = *(const short8*)(zsrc);                                     \
            Z1 = *(const short8*)(zsrc + 8);                                 \
            Z2 = *(const short8*)(zsrc + 16);                                \
            Z3 = *(const short8*)(zsrc + 24);                                \
        } while (0)

    #define WRITET(buf, A0, A1, Z0, Z1, Z2, Z3)                              \
        do {                                                                 \
            if (t < 128) *(short8*)&As[buf][ar][ac] = cvt8(A0, A1);          \
            *(short8*)&Zs[buf][zo][zk]      = Z0;                            \
            *(short8*)&Zs[buf][zo][zk + 8]  = Z1;                            \
            *(short8*)&Zs[buf][zo][zk + 16] = Z2;                            \
            *(short8*)&Zs[buf][zo][zk + 24] = Z3;                            \
        } while (0)

    #define MFMAS(cur)                                                       \
        do {                                                                 \
            _Pragma("unroll")                                                \
            for (int ks = 0; ks < 64; ks += 32) {                            \
                short8 af = *(const short8*)&As[cur][l15][ks + kgrp];        \
                short8 bf0 = *(const short8*)&Zs[cur][w * 32 + l15][ks + kgrp];       \
                short8 bf1 = *(const short8*)&Zs[cur][w * 32 + 16 + l15][ks + kgrp];  \
                acc[0] = __builtin_amdgcn_mfma_f32_16x16x32_bf16(af, bf0, acc[0], 0, 0, 0); \
                acc[1] = __builtin_amdgcn_mfma_f32_16x16x32_bf16(af, bf1, acc[1], 0, 0, 0); \
            }                                                                \
        } while (0)

    // prologue: tile0 -> buf0; tile1 -> set P
    LOADT(pa0, pa1, pz0, pz1, pz2, pz3, 0);
    WRITET(0, pa0, pa1, pz0, pz1, pz2, pz3);
    LOADT(pa0, pa1, pz0, pz1, pz2, pz3, 64);
    __syncthreads();

    // 32 K-steps, unrolled x2 with named set roles (P holds it+1, Q gets it+2)
    for (int it = 0; it < 32; it += 2) {
        // even iter: cur = buf0
        if (it + 2 < 32) LOADT(qa0, qa1, qz0, qz1, qz2, qz3, (it + 2) * 64);
        MFMAS(0);
        if (it + 1 < 32) WRITET(1, pa0, pa1, pz0, pz1, pz2, pz3);
        __syncthreads();
        // odd iter: cur = buf1  (roles swapped: Q holds it+2, P gets it+3)
        if (it + 1 < 32) {
            if (it + 3 < 32) LOADT(pa0, pa1, pz0, pz1, pz2, pz3, (it + 3) * 64);
            MFMAS(1);
            if (it + 2 < 32) WRITET(0, qa0, qa1, qz0, qz1, qz2, qz3);
            __syncthreads();
        }
    }

    int drow = (lane >> 4) * 4;
    #pragma unroll
    for (int tt = 0; tt < 2; ++tt) {
        int o = w * 32 + tt * 16 + l15;
        float bv = bias[o];
        #pragma unroll
        for (int r = 0; r < 4; ++r) {
            int n = n0 + drow + r;
            float dv = dinv[b * NN + n];
            out[((size_t)b * NN + n) * FF + o] = dv * acc[tt][r] + bv;
        }
    }
    #undef LOADT
    #undef WRITET
    #undef MFMAS
}

extern "C" void kernel_launch(void* const* d_in, const int* in_sizes, int n_in,
                              void* d_out, int out_size, void* d_ws, size_t ws_size,
                              hipStream_t stream) {
    // Bind inputs by element count (all distinct; order-proof):
    const float *X = nullptr, *A = nullptr, *W = nullptr, *bias = nullptr;
    for (int i = 0; i < n_in; ++i) {
        switch (in_sizes[i]) {
            case 16777216: A    = (const float*)d_in[i]; break;  // [4,2048,2048]
            case 1048576:  X    = (const float*)d_in[i]; break;  // [4,2048,128]
            case 16384:    W    = (const float*)d_in[i]; break;  // [128,128]
            case 128:      bias = (const float*)d_in[i]; break;  // [128]
            default: break;
        }
    }
    float* out = (float*)d_out;
    if (!X || !A || !W || !bias) return;        // signature: absmax 0.7578125
    if (out_size != 4 * NN * FF) return;
    if (ws_size < (size_t)WS_NEED) return;

    float* dinv        = (float*)d_ws;                            // 32 KB
    unsigned short* Zt = (unsigned short*)((char*)d_ws + 32768);  // 2 MB bf16

    k1_deg<<<4 * NN, 256, 0, stream>>>(A, dinv);
    k2_zt<<<256, 256, 0, stream>>>(X, W, dinv, Zt);
    k3_mfma<<<512, 256, 0, stream>>>(A, Zt, dinv, bias, out);
}